// Round 1
// baseline (418.925 us; speedup 1.0000x reference)
//
#include <hip/hip_runtime.h>
#include <hip/hip_fp16.h>

// Problem constants (fixed by the reference setup)
#define N_NODES 50000
#define IN_DIM 256
#define OUT_DIM 128
#define NNZ 800000          // nnz for feat, adj1, adj2 each
#define SCAN_N (3 * N_NODES)        // 150000 row counters (feat | adj1 | adj2)
#define TOTAL_NNZ (3 * NNZ)         // 2.4M sorted entries
#define SCAN_BLOCKS ((SCAN_N + 255) / 256)   // 586
#define NPART 8                      // one row-partition per XCD
#define PART_W (N_NODES / NPART)     // 6250 rows per partition

// Per-partition bucket capacity for the two-level sort.
// Expected count = 2.4M/8 = 300000, sigma = sqrt(2.4M*(1/8)*(7/8)) ~ 512.
// 310016 = 300000 + ~19.6 sigma, and a multiple of 256.
#define BCAP 310016
#define BBLK (BCAP / 256)            // 1211 blocks per partition for bucket passes

// Native clang vector types — __builtin_nontemporal_* requires these.
typedef float vf4 __attribute__((ext_vector_type(4)));

// Packed entry: [col:16 | fp16(val):16].  adj cols < 50000 < 65536, feat cols < 256.
static __device__ __forceinline__ unsigned pack_cv(int c, float v) {
    return ((unsigned)c << 16) | (unsigned)__half_as_ushort(__float2half(v));
}
static __device__ __forceinline__ int   upk_c(unsigned pk) { return (int)(pk >> 16); }
static __device__ __forceinline__ float upk_v(unsigned pk) {
    return __half2float(__ushort_as_half((unsigned short)(pk & 0xffffu)));
}
static __device__ __forceinline__ float h2f(unsigned short h) {
    return __half2float(__ushort_as_half(h));
}

// -----------------------------------------------------------------------------
// CSR build, two-level counting sort:
//   Pass A (bucket_kernel): read every edge ONCE, LDS-group by partition
//     (row/6250), append each partition's chunk to a contiguous per-partition
//     bucket (6 B/entry: spack-format u32 + u16 [seg:2|row_local:13]).
//   Pass B (bucket_hist_kernel): partition p's blocks (blockIdx&7 == p -> one
//     XCD) read only bucket p sequentially and histogram into cnt (XCD-local).
//   scan (unchanged): global exclusive scan over 150K counters. Rows sorted
//     globally => each partition's rows remain contiguous per segment, so the
//     gather kernels are untouched.
//   Pass C (bucket_scatter_kernel): re-read bucket p, cursor-atomic, store the
//     pre-packed u32 into spack. Cursors + destinations XCD-local; only the
//     partition's own ~1.9MB bucket flows through that L2, so partial spack
//     lines survive and merge (the old 8x-rescan version thrashed L2: 104 MB
//     WRITE_SIZE for 9.6 MB of payload).
// -----------------------------------------------------------------------------
__global__ void bucket_kernel(const int* __restrict__ fr, const int* __restrict__ fc,
                              const float* __restrict__ fv,
                              const int* __restrict__ a1r, const int* __restrict__ a1c,
                              const float* __restrict__ a1v,
                              const int* __restrict__ a2r, const int* __restrict__ a2c,
                              const float* __restrict__ a2v,
                              int* __restrict__ bcur,
                              unsigned* __restrict__ gpack,
                              unsigned short* __restrict__ gmeta) {
    __shared__ int cnt8[8];
    __shared__ int offc[8];              // exclusive scan of cnt8 (bucket starts)
    __shared__ int gbase[8];             // global append base per bucket
    __shared__ unsigned spk[768];        // staging, grouped by bucket
    __shared__ unsigned short smeta[768];
    int t = threadIdx.x;
    if (t < 8) cnt8[t] = 0;
    __syncthreads();

    int e = blockIdx.x * 256 + t;        // NNZ = 3125 * 256, no tail
    int r[3]; unsigned pk[3]; int loc[3]; int pb[3];
    r[0] = __builtin_nontemporal_load(&fr[e]);
    pk[0] = pack_cv(__builtin_nontemporal_load(&fc[e]),
                    __builtin_nontemporal_load(&fv[e]));
    r[1] = __builtin_nontemporal_load(&a1r[e]);
    pk[1] = pack_cv(__builtin_nontemporal_load(&a1c[e]),
                    __builtin_nontemporal_load(&a1v[e]));
    r[2] = __builtin_nontemporal_load(&a2r[e]);
    pk[2] = pack_cv(__builtin_nontemporal_load(&a2c[e]),
                    __builtin_nontemporal_load(&a2v[e]));
#pragma unroll
    for (int s = 0; s < 3; ++s) {
        pb[s] = r[s] / PART_W;
        loc[s] = atomicAdd(&cnt8[pb[s]], 1);
    }
    __syncthreads();
    if (t < 8) gbase[t] = atomicAdd(&bcur[t], cnt8[t]);
    if (t == 0) {
        int acc = 0;
#pragma unroll
        for (int q = 0; q < 8; ++q) { offc[q] = acc; acc += cnt8[q]; }
    }
    __syncthreads();
#pragma unroll
    for (int s = 0; s < 3; ++s) {
        int pos = offc[pb[s]] + loc[s];
        spk[pos] = pk[s];
        smeta[pos] = (unsigned short)((s << 13) | (r[s] - pb[s] * PART_W));
    }
    __syncthreads();
    // Coalesced write-out: consecutive threads hit consecutive global slots
    // within each bucket chunk (avg ~96 entries/chunk).
#pragma unroll
    for (int k = 0; k < 3; ++k) {
        int i = t + k * 256;
        int q = 0;
#pragma unroll
        for (int b = 1; b < 8; ++b) q += (i >= offc[b]);
        int g = q * BCAP + gbase[q] + (i - offc[q]);
        gpack[g] = spk[i];
        gmeta[g] = smeta[i];
    }
}

__global__ void bucket_hist_kernel(const unsigned short* __restrict__ gmeta,
                                   const int* __restrict__ bcur,
                                   int* __restrict__ cnt) {
    int p = blockIdx.x & (NPART - 1);
    int e = (blockIdx.x >> 3) * 256 + threadIdx.x;
    if (e >= bcur[p]) return;
    unsigned m = gmeta[p * BCAP + e];
    int gr = (int)(m >> 13) * N_NODES + p * PART_W + (int)(m & 8191u);
    atomicAdd(&cnt[gr], 1);
}

__global__ void bucket_scatter_kernel(const unsigned* __restrict__ gpack,
                                      const unsigned short* __restrict__ gmeta,
                                      const int* __restrict__ bcur,
                                      int* __restrict__ cursor,
                                      unsigned* __restrict__ spack) {
    int p = blockIdx.x & (NPART - 1);
    int e = (blockIdx.x >> 3) * 256 + threadIdx.x;
    if (e >= bcur[p]) return;
    unsigned m = gmeta[p * BCAP + e];
    int gr = (int)(m >> 13) * N_NODES + p * PART_W + (int)(m & 8191u);
    int pos = atomicAdd(&cursor[gr], 1);
    spack[pos] = gpack[p * BCAP + e];
}

__global__ void scan_block_kernel(const int* __restrict__ cnt,
                                  int* __restrict__ starts,
                                  int* __restrict__ bsum) {
    __shared__ int tmp[256];
    int g = blockIdx.x * 256 + threadIdx.x;
    int v = (g < SCAN_N) ? cnt[g] : 0;
    tmp[threadIdx.x] = v;
    __syncthreads();
    for (int off = 1; off < 256; off <<= 1) {
        int t = (threadIdx.x >= off) ? tmp[threadIdx.x - off] : 0;
        __syncthreads();
        tmp[threadIdx.x] += t;
        __syncthreads();
    }
    int incl = tmp[threadIdx.x];
    if (g < SCAN_N) starts[g] = incl - v;          // exclusive
    if (threadIdx.x == 255) bsum[blockIdx.x] = incl;
}

__global__ void scan_bsum_kernel(int* __restrict__ bsum, int nb) {
    __shared__ int tmp[1024];
    int t = threadIdx.x;
    int v = (t < nb) ? bsum[t] : 0;
    tmp[t] = v;
    __syncthreads();
    for (int off = 1; off < 1024; off <<= 1) {
        int x = (t >= off) ? tmp[t - off] : 0;
        __syncthreads();
        tmp[t] += x;
        __syncthreads();
    }
    if (t < nb) bsum[t] = tmp[t] - v;              // exclusive block offsets
}

__global__ void scan_add_kernel(int* __restrict__ starts,
                                const int* __restrict__ bsum,
                                int* __restrict__ cursor) {
    int g = blockIdx.x * 256 + threadIdx.x;
    if (g < SCAN_N) {
        int s = starts[g] + bsum[blockIdx.x];
        starts[g] = s;
        cursor[g] = s;
    }
}

// -----------------------------------------------------------------------------
// Phase 1: per-row gather  xw{1,2}[r,:] = sum_e v_e * W{1,2}[c_e,:]
// 32-lane row group: ONE coalesced load of up to 32 packed records, then
// shfl-broadcast; j-loop unrolled x4 so 8 independent W loads are in flight.
// xw output is fp16 (halves phase-2 gather bytes; |xw|<8 so fp16 is safe).
// -----------------------------------------------------------------------------
__global__ void feat_gather_kernel(const int* __restrict__ starts,
                                   const unsigned* __restrict__ spack,
                                   const float4* __restrict__ W1,
                                   const float4* __restrict__ W2,
                                   ushort4* __restrict__ xw1h,
                                   ushort4* __restrict__ xw2h) {
    int lane = threadIdx.x & 31;
    int sub  = threadIdx.x >> 5;
    int r = blockIdx.x * 8 + sub;
    if (r >= N_NODES) return;
    int s = starts[r];
    int e = starts[r + 1];            // starts[50000] == 800000 (adj1 base)
    float4 a1 = make_float4(0.f, 0.f, 0.f, 0.f);
    float4 a2 = make_float4(0.f, 0.f, 0.f, 0.f);
    for (int base = s; base < e; base += 32) {
        int n = e - base;
        int m = (n < 32) ? n : 32;
        unsigned pk = (lane < m) ? spack[base + lane] : 0u;
        int j = 0;
        for (; j + 3 < m; j += 4) {
            unsigned p0 = __shfl(pk, j,     32);
            unsigned p1 = __shfl(pk, j + 1, 32);
            unsigned p2 = __shfl(pk, j + 2, 32);
            unsigned p3 = __shfl(pk, j + 3, 32);
            int c0 = upk_c(p0), c1 = upk_c(p1), c2 = upk_c(p2), c3 = upk_c(p3);
            float v0 = upk_v(p0), v1 = upk_v(p1), v2 = upk_v(p2), v3 = upk_v(p3);
            float4 w10 = W1[c0 * 32 + lane], w20 = W2[c0 * 32 + lane];
            float4 w11 = W1[c1 * 32 + lane], w21 = W2[c1 * 32 + lane];
            float4 w12 = W1[c2 * 32 + lane], w22 = W2[c2 * 32 + lane];
            float4 w13 = W1[c3 * 32 + lane], w23 = W2[c3 * 32 + lane];
            a1.x += v0 * w10.x; a1.y += v0 * w10.y; a1.z += v0 * w10.z; a1.w += v0 * w10.w;
            a2.x += v0 * w20.x; a2.y += v0 * w20.y; a2.z += v0 * w20.z; a2.w += v0 * w20.w;
            a1.x += v1 * w11.x; a1.y += v1 * w11.y; a1.z += v1 * w11.z; a1.w += v1 * w11.w;
            a2.x += v1 * w21.x; a2.y += v1 * w21.y; a2.z += v1 * w21.z; a2.w += v1 * w21.w;
            a1.x += v2 * w12.x; a1.y += v2 * w12.y; a1.z += v2 * w12.z; a1.w += v2 * w12.w;
            a2.x += v2 * w22.x; a2.y += v2 * w22.y; a2.z += v2 * w22.z; a2.w += v2 * w22.w;
            a1.x += v3 * w13.x; a1.y += v3 * w13.y; a1.z += v3 * w13.z; a1.w += v3 * w13.w;
            a2.x += v3 * w23.x; a2.y += v3 * w23.y; a2.z += v3 * w23.z; a2.w += v3 * w23.w;
        }
        for (; j < m; ++j) {
            unsigned pj = __shfl(pk, j, 32);
            int c = upk_c(pj);
            float v = upk_v(pj);
            float4 w1 = W1[c * 32 + lane];
            float4 w2 = W2[c * 32 + lane];
            a1.x += v * w1.x; a1.y += v * w1.y; a1.z += v * w1.z; a1.w += v * w1.w;
            a2.x += v * w2.x; a2.y += v * w2.y; a2.z += v * w2.z; a2.w += v * w2.w;
        }
    }
    ushort4 q1, q2;
    q1.x = __half_as_ushort(__float2half(a1.x)); q1.y = __half_as_ushort(__float2half(a1.y));
    q1.z = __half_as_ushort(__float2half(a1.z)); q1.w = __half_as_ushort(__float2half(a1.w));
    q2.x = __half_as_ushort(__float2half(a2.x)); q2.y = __half_as_ushort(__float2half(a2.y));
    q2.z = __half_as_ushort(__float2half(a2.z)); q2.w = __half_as_ushort(__float2half(a2.w));
    xw1h[r * 32 + lane] = q1;
    xw2h[r * 32 + lane] = q2;
}

// -----------------------------------------------------------------------------
// Phase 2: out[r,:] = relu( sum_adj1 v*xw1[c,:] + sum_adj2 v*xw2[c,:] )
// Same shfl-broadcast + x4 unroll; xw gathers are fp16 (8B/lane); out fp32
// written with nt stores (single-touch, keep xw resident in L2).
// -----------------------------------------------------------------------------
__global__ void adj_gather_kernel(const int* __restrict__ starts,
                                  const unsigned* __restrict__ spack,
                                  const ushort4* __restrict__ xw1h,
                                  const ushort4* __restrict__ xw2h,
                                  vf4* __restrict__ out) {
    int lane = threadIdx.x & 31;
    int sub  = threadIdx.x >> 5;
    int r = blockIdx.x * 8 + sub;
    if (r >= N_NODES) return;
    float4 acc = make_float4(0.f, 0.f, 0.f, 0.f);

    for (int rel = 0; rel < 2; ++rel) {
        int s = starts[(1 + rel) * N_NODES + r];
        int e = (rel == 1 && r == N_NODES - 1) ? TOTAL_NNZ
                                               : starts[(1 + rel) * N_NODES + r + 1];
        const ushort4* __restrict__ xw = (rel == 0) ? xw1h : xw2h;
        for (int base = s; base < e; base += 32) {
            int n = e - base;
            int m = (n < 32) ? n : 32;
            unsigned pk = (lane < m) ? spack[base + lane] : 0u;
            int j = 0;
            for (; j + 3 < m; j += 4) {
                unsigned p0 = __shfl(pk, j,     32);
                unsigned p1 = __shfl(pk, j + 1, 32);
                unsigned p2 = __shfl(pk, j + 2, 32);
                unsigned p3 = __shfl(pk, j + 3, 32);
                int c0 = upk_c(p0), c1 = upk_c(p1), c2 = upk_c(p2), c3 = upk_c(p3);
                float v0 = upk_v(p0), v1 = upk_v(p1), v2 = upk_v(p2), v3 = upk_v(p3);
                ushort4 x0 = xw[c0 * 32 + lane];
                ushort4 x1 = xw[c1 * 32 + lane];
                ushort4 x2 = xw[c2 * 32 + lane];
                ushort4 x3 = xw[c3 * 32 + lane];
                acc.x += v0 * h2f(x0.x); acc.y += v0 * h2f(x0.y);
                acc.z += v0 * h2f(x0.z); acc.w += v0 * h2f(x0.w);
                acc.x += v1 * h2f(x1.x); acc.y += v1 * h2f(x1.y);
                acc.z += v1 * h2f(x1.z); acc.w += v1 * h2f(x1.w);
                acc.x += v2 * h2f(x2.x); acc.y += v2 * h2f(x2.y);
                acc.z += v2 * h2f(x2.z); acc.w += v2 * h2f(x2.w);
                acc.x += v3 * h2f(x3.x); acc.y += v3 * h2f(x3.y);
                acc.z += v3 * h2f(x3.z); acc.w += v3 * h2f(x3.w);
            }
            for (; j < m; ++j) {
                unsigned pj = __shfl(pk, j, 32);
                int c = upk_c(pj);
                float v = upk_v(pj);
                ushort4 x = xw[c * 32 + lane];
                acc.x += v * h2f(x.x); acc.y += v * h2f(x.y);
                acc.z += v * h2f(x.z); acc.w += v * h2f(x.w);
            }
        }
    }
    vf4 res;
    res.x = fmaxf(acc.x, 0.f); res.y = fmaxf(acc.y, 0.f);
    res.z = fmaxf(acc.z, 0.f); res.w = fmaxf(acc.w, 0.f);
    __builtin_nontemporal_store(res, &out[r * 32 + lane]);
}

extern "C" void kernel_launch(void* const* d_in, const int* in_sizes, int n_in,
                              void* d_out, int out_size, void* d_ws, size_t ws_size,
                              hipStream_t stream) {
    const int*   feat_row  = (const int*)  d_in[0];
    const int*   feat_col  = (const int*)  d_in[1];
    const float* feat_vals = (const float*)d_in[2];
    const int*   adj1_row  = (const int*)  d_in[3];
    const int*   adj1_col  = (const int*)  d_in[4];
    const float* adj1_vals = (const float*)d_in[5];
    const int*   adj2_row  = (const int*)  d_in[6];
    const int*   adj2_col  = (const int*)  d_in[7];
    const float* adj2_vals = (const float*)d_in[8];
    const float* W1        = (const float*)d_in[9];
    const float* W2        = (const float*)d_in[10];

    // Workspace layout (all offsets 16B-aligned; total ~52 MB)
    char* ws = (char*)d_ws;
    ushort4*  xw1h  = (ushort4*)ws;             ws += (size_t)N_NODES * OUT_DIM * 2;  // 12.8 MB
    ushort4*  xw2h  = (ushort4*)ws;             ws += (size_t)N_NODES * OUT_DIM * 2;  // 12.8 MB
    unsigned* spack = (unsigned*)ws;            ws += (size_t)TOTAL_NNZ * 4;          // 9.6 MB
    int*      cnt   = (int*)ws;                 ws += (size_t)SCAN_N * 4;             // 600 KB
    int*      bcur  = (int*)ws;                 ws += 16 * 4;                         // 8 used, padded
    int*      starts= (int*)ws;                 ws += (size_t)SCAN_N * 4;             // 600 KB
    int*      cursor= (int*)ws;                 ws += (size_t)SCAN_N * 4;             // 600 KB
    int*      bsum  = (int*)ws;                 ws += 1024 * 4;
    unsigned* gpack = (unsigned*)ws;            ws += (size_t)NPART * BCAP * 4;       // 9.9 MB
    unsigned short* gmeta = (unsigned short*)ws; ws += (size_t)NPART * BCAP * 2;      // 5.0 MB

    // Zero histogram counters + bucket cursors in one memset (bcur follows cnt).
    (void)hipMemsetAsync(cnt, 0, SCAN_N * sizeof(int) + 16 * sizeof(int), stream);

    const int block = 256;

    // Pass A: single read of all 9 streams, LDS-bucket by row partition.
    bucket_kernel<<<NNZ / block, block, 0, stream>>>(
        feat_row, feat_col, feat_vals,
        adj1_row, adj1_col, adj1_vals,
        adj2_row, adj2_col, adj2_vals,
        bcur, gpack, gmeta);

    // Pass B: XCD-local histogram from buckets (blockIdx&7 = partition).
    const int grid_bkt = NPART * BBLK;                           // 9688
    bucket_hist_kernel<<<grid_bkt, block, 0, stream>>>(gmeta, bcur, cnt);

    scan_block_kernel<<<SCAN_BLOCKS, 256, 0, stream>>>(cnt, starts, bsum);
    scan_bsum_kernel<<<1, 1024, 0, stream>>>(bsum, SCAN_BLOCKS);
    scan_add_kernel<<<SCAN_BLOCKS, 256, 0, stream>>>(starts, bsum, cursor);

    // Pass C: XCD-local scatter from buckets into the row-sorted spack.
    bucket_scatter_kernel<<<grid_bkt, block, 0, stream>>>(
        gpack, gmeta, bcur, cursor, spack);

    const int grid_rows = N_NODES / 8;                           // 6250 blocks, 8 rows each
    feat_gather_kernel<<<grid_rows, 256, 0, stream>>>(
        starts, spack, (const float4*)W1, (const float4*)W2, xw1h, xw2h);
    adj_gather_kernel<<<grid_rows, 256, 0, stream>>>(
        starts, spack, xw1h, xw2h, (vf4*)d_out);
}

// Round 2
// 277.448 us; speedup vs baseline: 1.5099x; 1.5099x over previous
//
#include <hip/hip_runtime.h>
#include <hip/hip_fp16.h>

// Problem constants (fixed by the reference setup)
#define N_NODES 50000
#define IN_DIM 256
#define OUT_DIM 128
#define NNZ 800000          // nnz for feat, adj1, adj2 each
#define SCAN_N (3 * N_NODES)        // 150000 row counters (feat | adj1 | adj2)
#define TOTAL_NNZ (3 * NNZ)         // 2.4M sorted entries
#define SCAN_BLOCKS ((SCAN_N + 255) / 256)   // 586
#define NPART 8                      // one row-partition per XCD
#define PART_W (N_NODES / NPART)     // 6250 rows per partition

// Level-1 per-partition bucket capacity.
// Expected 2.4M/8 = 300000, sigma ~512; 310016 = +19.6 sigma, multiple of 256.
#define BCAP 310016

// Level-2 sub-buckets: 64 per partition, 98 rows each (64*98=6272 >= 6250).
// Expected entries 2.4M*98/50000 = 4704, sigma ~68; 6144 = +21 sigma = 12*512.
#define NSUB 64
#define SUBW 98
#define SUBCAP 6144
#define ENT_B 4096                   // entries per subbucket_kernel block (256 thr x 16)
#define BBLK_B ((BCAP + ENT_B - 1) / ENT_B)   // 76 blocks per partition

// Native clang vector types — __builtin_nontemporal_* requires these.
typedef float vf4 __attribute__((ext_vector_type(4)));

// Packed entry: [col:16 | fp16(val):16].  adj cols < 50000 < 65536, feat cols < 256.
static __device__ __forceinline__ unsigned pack_cv(int c, float v) {
    return ((unsigned)c << 16) | (unsigned)__half_as_ushort(__float2half(v));
}
static __device__ __forceinline__ int   upk_c(unsigned pk) { return (int)(pk >> 16); }
static __device__ __forceinline__ float upk_v(unsigned pk) {
    return __half2float(__ushort_as_half((unsigned short)(pk & 0xffffu)));
}
static __device__ __forceinline__ float h2f(unsigned short h) {
    return __half2float(__ushort_as_half(h));
}

// -----------------------------------------------------------------------------
// CSR build, three-level counting sort with NO scattered global stores:
//   A (bucket_kernel):    read every edge once, LDS-group by partition (row/6250),
//                         append chunks (~96 entries) to per-partition buckets.
//   B (subbucket_kernel): read partition bucket, LDS-group by sub-bucket
//                         (98-row ranges, 64/partition), append chunks (~64
//                         entries) to per-sub-bucket storage. blockIdx&7 = p.
//   C1 (subhist_kernel):  per sub-bucket LDS histogram over 294 (seg,row) keys,
//                         write cnt with plain coalesced stores (each (seg,row)
//                         belongs to exactly one sub-bucket -> no atomics, no
//                         memset of cnt).
//   scan:                 global exclusive scan over 150K counters -> starts.
//   C2 (sort_write_kernel): per sub-bucket LDS counting sort; since the block
//                         owns ALL entries of its 98 rows, sorted output maps
//                         to THREE CONTIGUOUS ranges of spack (one/segment) ->
//                         all global writes are coalesced full lines. The old
//                         cursor-atomic scatter (103 MB HBM write for a 9.6 MB
//                         payload: ~43 B written back per 4 B store) is gone.
// -----------------------------------------------------------------------------
__global__ void bucket_kernel(const int* __restrict__ fr, const int* __restrict__ fc,
                              const float* __restrict__ fv,
                              const int* __restrict__ a1r, const int* __restrict__ a1c,
                              const float* __restrict__ a1v,
                              const int* __restrict__ a2r, const int* __restrict__ a2c,
                              const float* __restrict__ a2v,
                              int* __restrict__ bcur,
                              unsigned* __restrict__ gpack,
                              unsigned short* __restrict__ gmeta) {
    __shared__ int cnt8[8];
    __shared__ int offc[8];              // exclusive scan of cnt8 (bucket starts)
    __shared__ int gbase[8];             // global append base per bucket
    __shared__ unsigned spk[768];        // staging, grouped by bucket
    __shared__ unsigned short smeta[768];
    int t = threadIdx.x;
    if (t < 8) cnt8[t] = 0;
    __syncthreads();

    int e = blockIdx.x * 256 + t;        // NNZ = 3125 * 256, no tail
    int r[3]; unsigned pk[3]; int loc[3]; int pb[3];
    r[0] = __builtin_nontemporal_load(&fr[e]);
    pk[0] = pack_cv(__builtin_nontemporal_load(&fc[e]),
                    __builtin_nontemporal_load(&fv[e]));
    r[1] = __builtin_nontemporal_load(&a1r[e]);
    pk[1] = pack_cv(__builtin_nontemporal_load(&a1c[e]),
                    __builtin_nontemporal_load(&a1v[e]));
    r[2] = __builtin_nontemporal_load(&a2r[e]);
    pk[2] = pack_cv(__builtin_nontemporal_load(&a2c[e]),
                    __builtin_nontemporal_load(&a2v[e]));
#pragma unroll
    for (int s = 0; s < 3; ++s) {
        pb[s] = r[s] / PART_W;
        loc[s] = atomicAdd(&cnt8[pb[s]], 1);
    }
    __syncthreads();
    if (t < 8) gbase[t] = atomicAdd(&bcur[t], cnt8[t]);
    if (t == 0) {
        int acc = 0;
#pragma unroll
        for (int q = 0; q < 8; ++q) { offc[q] = acc; acc += cnt8[q]; }
    }
    __syncthreads();
#pragma unroll
    for (int s = 0; s < 3; ++s) {
        int pos = offc[pb[s]] + loc[s];
        spk[pos] = pk[s];
        smeta[pos] = (unsigned short)((s << 13) | (r[s] - pb[s] * PART_W));
    }
    __syncthreads();
#pragma unroll
    for (int k = 0; k < 3; ++k) {
        int i = t + k * 256;
        int q = 0;
#pragma unroll
        for (int b = 1; b < 8; ++b) q += (i >= offc[b]);
        int g = q * BCAP + gbase[q] + (i - offc[q]);
        gpack[g] = spk[i];
        gmeta[g] = smeta[i];
    }
}

// Pass B: partition bucket -> 64 sub-buckets (98-row ranges). blockIdx&7 = p.
__global__ void subbucket_kernel(const unsigned* __restrict__ gpack1,
                                 const unsigned short* __restrict__ gmeta1,
                                 const int* __restrict__ bcur,
                                 int* __restrict__ subcur,
                                 unsigned* __restrict__ gpack2,
                                 unsigned short* __restrict__ gmeta2) {
    int p = blockIdx.x & (NPART - 1);
    int chunk = blockIdx.x >> 3;
    int base = chunk * ENT_B;
    int n = bcur[p];
    int cnt = n - base;
    if (cnt <= 0) return;                // uniform across block
    if (cnt > ENT_B) cnt = ENT_B;
    __shared__ int c64[NSUB], off[NSUB], gb[NSUB];
    __shared__ unsigned spk[ENT_B];
    __shared__ unsigned short smt[ENT_B];
    int t = threadIdx.x;
    if (t < NSUB) c64[t] = 0;
    __syncthreads();
    unsigned pk[16]; unsigned short mt[16]; int loc[16]; int sb[16];
#pragma unroll
    for (int k = 0; k < 16; ++k) {
        int i = t + k * 256;
        if (i < cnt) {
            pk[k] = gpack1[p * BCAP + base + i];
            mt[k] = gmeta1[p * BCAP + base + i];
            sb[k] = (int)(mt[k] & 8191u) / SUBW;
            loc[k] = atomicAdd(&c64[sb[k]], 1);
        } else sb[k] = -1;
    }
    __syncthreads();
    if (t == 0) {
        int a = 0;
#pragma unroll
        for (int q = 0; q < NSUB; ++q) { off[q] = a; a += c64[q]; }
    }
    __syncthreads();
    if (t < NSUB && c64[t] > 0) gb[t] = atomicAdd(&subcur[p * NSUB + t], c64[t]);
    __syncthreads();
#pragma unroll
    for (int k = 0; k < 16; ++k) {
        if (sb[k] >= 0) {
            int pos = off[sb[k]] + loc[k];
            spk[pos] = pk[k];
            smt[pos] = mt[k];
        }
    }
    __syncthreads();
    // Coalesced write-out: ~64-entry contiguous chunks per sub-bucket.
    for (int i = t; i < cnt; i += 256) {
        unsigned short m = smt[i];
        int s2 = (int)(m & 8191u) / SUBW;
        int g = (p * NSUB + s2) * SUBCAP + gb[s2] + (i - off[s2]);
        gpack2[g] = spk[i];
        gmeta2[g] = m;
    }
}

// Pass C1: per-sub-bucket histogram -> cnt (plain stores, covers all of cnt).
__global__ __launch_bounds__(512) void subhist_kernel(
        const unsigned short* __restrict__ gmeta2,
        const int* __restrict__ subcur,
        int* __restrict__ cnt) {
    int p = blockIdx.x & (NPART - 1);
    int sub = blockIdx.x >> 3;
    int n = subcur[p * NSUB + sub];
    __shared__ int h[512];
    int t = threadIdx.x;
    h[t] = 0;
    __syncthreads();
    long base = (long)(p * NSUB + sub) * SUBCAP;
    for (int i = t; i < n; i += 512) {
        unsigned short m = gmeta2[base + i];
        int key = (int)(m >> 13) * SUBW + ((int)(m & 8191u) - sub * SUBW);
        atomicAdd(&h[key], 1);
    }
    __syncthreads();
    if (t < 3 * SUBW) {
        int s = t / SUBW, d = t - s * SUBW;
        int rl = sub * SUBW + d;
        if (rl < PART_W) cnt[s * N_NODES + p * PART_W + rl] = h[t];
    }
}

__global__ void scan_block_kernel(const int* __restrict__ cnt,
                                  int* __restrict__ starts,
                                  int* __restrict__ bsum) {
    __shared__ int tmp[256];
    int g = blockIdx.x * 256 + threadIdx.x;
    int v = (g < SCAN_N) ? cnt[g] : 0;
    tmp[threadIdx.x] = v;
    __syncthreads();
    for (int off = 1; off < 256; off <<= 1) {
        int t = (threadIdx.x >= off) ? tmp[threadIdx.x - off] : 0;
        __syncthreads();
        tmp[threadIdx.x] += t;
        __syncthreads();
    }
    int incl = tmp[threadIdx.x];
    if (g < SCAN_N) starts[g] = incl - v;          // exclusive
    if (threadIdx.x == 255) bsum[blockIdx.x] = incl;
}

__global__ void scan_bsum_kernel(int* __restrict__ bsum, int nb) {
    __shared__ int tmp[1024];
    int t = threadIdx.x;
    int v = (t < nb) ? bsum[t] : 0;
    tmp[t] = v;
    __syncthreads();
    for (int off = 1; off < 1024; off <<= 1) {
        int x = (t >= off) ? tmp[t - off] : 0;
        __syncthreads();
        tmp[t] += x;
        __syncthreads();
    }
    if (t < nb) bsum[t] = tmp[t] - v;              // exclusive block offsets
}

__global__ void scan_add_kernel(int* __restrict__ starts,
                                const int* __restrict__ bsum) {
    int g = blockIdx.x * 256 + threadIdx.x;
    if (g < SCAN_N) starts[g] += bsum[blockIdx.x];
}

// Pass C2: LDS counting sort of one sub-bucket, then coalesced contiguous
// writes into spack (three contiguous global ranges, one per segment).
__global__ __launch_bounds__(512) void sort_write_kernel(
        const unsigned* __restrict__ gpack2,
        const unsigned short* __restrict__ gmeta2,
        const int* __restrict__ subcur,
        const int* __restrict__ starts,
        unsigned* __restrict__ spack) {
    int p = blockIdx.x & (NPART - 1);
    int sub = blockIdx.x >> 3;
    int n = subcur[p * NSUB + sub];
    __shared__ int h[512];
    __shared__ int e[512];
    __shared__ int cur[512];
    __shared__ unsigned sorted[SUBCAP];
    int t = threadIdx.x;
    h[t] = 0;
    __syncthreads();
    long base = (long)(p * NSUB + sub) * SUBCAP;
    unsigned pk[12]; short ky[12];
#pragma unroll
    for (int k = 0; k < 12; ++k) {           // SUBCAP = 12*512 exactly
        int i = t + k * 512;
        if (i < n) {
            pk[k] = gpack2[base + i];
            unsigned short m = gmeta2[base + i];
            int key = (int)(m >> 13) * SUBW + ((int)(m & 8191u) - sub * SUBW);
            ky[k] = (short)key;
            atomicAdd(&h[key], 1);
        } else ky[k] = -1;
    }
    __syncthreads();
    // Hillis-Steele inclusive scan over 512 slots (keys occupy [0,294)).
    e[t] = h[t];
    __syncthreads();
    for (int off = 1; off < 512; off <<= 1) {
        int v = (t >= off) ? e[t - off] : 0;
        __syncthreads();
        e[t] += v;
        __syncthreads();
    }
    int excl = e[t] - h[t];
    __syncthreads();
    e[t] = excl;
    cur[t] = excl;
    __syncthreads();
#pragma unroll
    for (int k = 0; k < 12; ++k) {
        if (ky[k] >= 0) {
            int pos = atomicAdd(&cur[ky[k]], 1);
            sorted[pos] = pk[k];
        }
    }
    __syncthreads();
    int s1 = e[SUBW];                         // local start of adj1 entries
    int s2 = e[2 * SUBW];                     // local start of adj2 entries
    int rb = p * PART_W + sub * SUBW;
    int gb0 = starts[rb];
    int gb1 = starts[N_NODES + rb];
    int gb2 = starts[2 * N_NODES + rb];
#pragma unroll
    for (int k = 0; k < 12; ++k) {
        int i = t + k * 512;
        if (i < n) {
            unsigned v = sorted[i];
            int dst;
            if (i < s1)      dst = gb0 + i;
            else if (i < s2) dst = gb1 + (i - s1);
            else             dst = gb2 + (i - s2);
            spack[dst] = v;
        }
    }
}

// -----------------------------------------------------------------------------
// Phase 1: per-row gather  xw{1,2}[r,:] = sum_e v_e * W{1,2}[c_e,:]
// -----------------------------------------------------------------------------
__global__ void feat_gather_kernel(const int* __restrict__ starts,
                                   const unsigned* __restrict__ spack,
                                   const float4* __restrict__ W1,
                                   const float4* __restrict__ W2,
                                   ushort4* __restrict__ xw1h,
                                   ushort4* __restrict__ xw2h) {
    int lane = threadIdx.x & 31;
    int sub  = threadIdx.x >> 5;
    int r = blockIdx.x * 8 + sub;
    if (r >= N_NODES) return;
    int s = starts[r];
    int e = starts[r + 1];            // starts[50000] == 800000 (adj1 base)
    float4 a1 = make_float4(0.f, 0.f, 0.f, 0.f);
    float4 a2 = make_float4(0.f, 0.f, 0.f, 0.f);
    for (int base = s; base < e; base += 32) {
        int n = e - base;
        int m = (n < 32) ? n : 32;
        unsigned pk = (lane < m) ? spack[base + lane] : 0u;
        int j = 0;
        for (; j + 3 < m; j += 4) {
            unsigned p0 = __shfl(pk, j,     32);
            unsigned p1 = __shfl(pk, j + 1, 32);
            unsigned p2 = __shfl(pk, j + 2, 32);
            unsigned p3 = __shfl(pk, j + 3, 32);
            int c0 = upk_c(p0), c1 = upk_c(p1), c2 = upk_c(p2), c3 = upk_c(p3);
            float v0 = upk_v(p0), v1 = upk_v(p1), v2 = upk_v(p2), v3 = upk_v(p3);
            float4 w10 = W1[c0 * 32 + lane], w20 = W2[c0 * 32 + lane];
            float4 w11 = W1[c1 * 32 + lane], w21 = W2[c1 * 32 + lane];
            float4 w12 = W1[c2 * 32 + lane], w22 = W2[c2 * 32 + lane];
            float4 w13 = W1[c3 * 32 + lane], w23 = W2[c3 * 32 + lane];
            a1.x += v0 * w10.x; a1.y += v0 * w10.y; a1.z += v0 * w10.z; a1.w += v0 * w10.w;
            a2.x += v0 * w20.x; a2.y += v0 * w20.y; a2.z += v0 * w20.z; a2.w += v0 * w20.w;
            a1.x += v1 * w11.x; a1.y += v1 * w11.y; a1.z += v1 * w11.z; a1.w += v1 * w11.w;
            a2.x += v1 * w21.x; a2.y += v1 * w21.y; a2.z += v1 * w21.z; a2.w += v1 * w21.w;
            a1.x += v2 * w12.x; a1.y += v2 * w12.y; a1.z += v2 * w12.z; a1.w += v2 * w12.w;
            a2.x += v2 * w22.x; a2.y += v2 * w22.y; a2.z += v2 * w22.z; a2.w += v2 * w22.w;
            a1.x += v3 * w13.x; a1.y += v3 * w13.y; a1.z += v3 * w13.z; a1.w += v3 * w13.w;
            a2.x += v3 * w23.x; a2.y += v3 * w23.y; a2.z += v3 * w23.z; a2.w += v3 * w23.w;
        }
        for (; j < m; ++j) {
            unsigned pj = __shfl(pk, j, 32);
            int c = upk_c(pj);
            float v = upk_v(pj);
            float4 w1 = W1[c * 32 + lane];
            float4 w2 = W2[c * 32 + lane];
            a1.x += v * w1.x; a1.y += v * w1.y; a1.z += v * w1.z; a1.w += v * w1.w;
            a2.x += v * w2.x; a2.y += v * w2.y; a2.z += v * w2.z; a2.w += v * w2.w;
        }
    }
    ushort4 q1, q2;
    q1.x = __half_as_ushort(__float2half(a1.x)); q1.y = __half_as_ushort(__float2half(a1.y));
    q1.z = __half_as_ushort(__float2half(a1.z)); q1.w = __half_as_ushort(__float2half(a1.w));
    q2.x = __half_as_ushort(__float2half(a2.x)); q2.y = __half_as_ushort(__float2half(a2.y));
    q2.z = __half_as_ushort(__float2half(a2.z)); q2.w = __half_as_ushort(__float2half(a2.w));
    xw1h[r * 32 + lane] = q1;
    xw2h[r * 32 + lane] = q2;
}

// -----------------------------------------------------------------------------
// Phase 2: out[r,:] = relu( sum_adj1 v*xw1[c,:] + sum_adj2 v*xw2[c,:] )
// -----------------------------------------------------------------------------
__global__ void adj_gather_kernel(const int* __restrict__ starts,
                                  const unsigned* __restrict__ spack,
                                  const ushort4* __restrict__ xw1h,
                                  const ushort4* __restrict__ xw2h,
                                  vf4* __restrict__ out) {
    int lane = threadIdx.x & 31;
    int sub  = threadIdx.x >> 5;
    int r = blockIdx.x * 8 + sub;
    if (r >= N_NODES) return;
    float4 acc = make_float4(0.f, 0.f, 0.f, 0.f);

    for (int rel = 0; rel < 2; ++rel) {
        int s = starts[(1 + rel) * N_NODES + r];
        int e = (rel == 1 && r == N_NODES - 1) ? TOTAL_NNZ
                                               : starts[(1 + rel) * N_NODES + r + 1];
        const ushort4* __restrict__ xw = (rel == 0) ? xw1h : xw2h;
        for (int base = s; base < e; base += 32) {
            int n = e - base;
            int m = (n < 32) ? n : 32;
            unsigned pk = (lane < m) ? spack[base + lane] : 0u;
            int j = 0;
            for (; j + 3 < m; j += 4) {
                unsigned p0 = __shfl(pk, j,     32);
                unsigned p1 = __shfl(pk, j + 1, 32);
                unsigned p2 = __shfl(pk, j + 2, 32);
                unsigned p3 = __shfl(pk, j + 3, 32);
                int c0 = upk_c(p0), c1 = upk_c(p1), c2 = upk_c(p2), c3 = upk_c(p3);
                float v0 = upk_v(p0), v1 = upk_v(p1), v2 = upk_v(p2), v3 = upk_v(p3);
                ushort4 x0 = xw[c0 * 32 + lane];
                ushort4 x1 = xw[c1 * 32 + lane];
                ushort4 x2 = xw[c2 * 32 + lane];
                ushort4 x3 = xw[c3 * 32 + lane];
                acc.x += v0 * h2f(x0.x); acc.y += v0 * h2f(x0.y);
                acc.z += v0 * h2f(x0.z); acc.w += v0 * h2f(x0.w);
                acc.x += v1 * h2f(x1.x); acc.y += v1 * h2f(x1.y);
                acc.z += v1 * h2f(x1.z); acc.w += v1 * h2f(x1.w);
                acc.x += v2 * h2f(x2.x); acc.y += v2 * h2f(x2.y);
                acc.z += v2 * h2f(x2.z); acc.w += v2 * h2f(x2.w);
                acc.x += v3 * h2f(x3.x); acc.y += v3 * h2f(x3.y);
                acc.z += v3 * h2f(x3.z); acc.w += v3 * h2f(x3.w);
            }
            for (; j < m; ++j) {
                unsigned pj = __shfl(pk, j, 32);
                int c = upk_c(pj);
                float v = upk_v(pj);
                ushort4 x = xw[c * 32 + lane];
                acc.x += v * h2f(x.x); acc.y += v * h2f(x.y);
                acc.z += v * h2f(x.z); acc.w += v * h2f(x.w);
            }
        }
    }
    vf4 res;
    res.x = fmaxf(acc.x, 0.f); res.y = fmaxf(acc.y, 0.f);
    res.z = fmaxf(acc.z, 0.f); res.w = fmaxf(acc.w, 0.f);
    __builtin_nontemporal_store(res, &out[r * 32 + lane]);
}

extern "C" void kernel_launch(void* const* d_in, const int* in_sizes, int n_in,
                              void* d_out, int out_size, void* d_ws, size_t ws_size,
                              hipStream_t stream) {
    const int*   feat_row  = (const int*)  d_in[0];
    const int*   feat_col  = (const int*)  d_in[1];
    const float* feat_vals = (const float*)d_in[2];
    const int*   adj1_row  = (const int*)  d_in[3];
    const int*   adj1_col  = (const int*)  d_in[4];
    const float* adj1_vals = (const float*)d_in[5];
    const int*   adj2_row  = (const int*)  d_in[6];
    const int*   adj2_col  = (const int*)  d_in[7];
    const float* adj2_vals = (const float*)d_in[8];
    const float* W1        = (const float*)d_in[9];
    const float* W2        = (const float*)d_in[10];

    // Workspace layout. Bucket storage (~33.8 MB) is dead after sort_write,
    // so xw1h/xw2h (25.6 MB) alias it. Total footprint ~44.6 MB.
    char* ws = (char*)d_ws;
    unsigned* spack = (unsigned*)ws;            ws += (size_t)TOTAL_NNZ * 4;          // 9.6 MB
    int*      cnt   = (int*)ws;                 ws += (size_t)SCAN_N * 4;             // 600 KB
    int*      starts= (int*)ws;                 ws += (size_t)SCAN_N * 4;             // 600 KB
    int*      bsum  = (int*)ws;                 ws += 1024 * 4;
    int*      bcur  = (int*)ws;                 ws += 16 * 4;                         // 8 used
    int*      subcur= (int*)ws;                 ws += (size_t)NPART * NSUB * 4;       // 2 KB
    char*     bkt   = ws;                                                             // bucket region
    unsigned* gpack1 = (unsigned*)bkt;
    unsigned short* gmeta1 = (unsigned short*)(bkt + (size_t)NPART * BCAP * 4);
    unsigned* gpack2 = (unsigned*)(bkt + (size_t)NPART * BCAP * 6);
    unsigned short* gmeta2 = (unsigned short*)(bkt + (size_t)NPART * BCAP * 6
                                                  + (size_t)NPART * NSUB * SUBCAP * 4);
    ushort4*  xw1h  = (ushort4*)bkt;                                     // alias (after C2)
    ushort4*  xw2h  = (ushort4*)(bkt + (size_t)N_NODES * OUT_DIM * 2);   // alias

    // Zero only bcur + subcur (adjacent, 528 ints). cnt is fully written by C1.
    (void)hipMemsetAsync(bcur, 0, (16 + NPART * NSUB) * sizeof(int), stream);

    const int block = 256;

    // A: single read of all 9 streams, LDS-bucket by row partition.
    bucket_kernel<<<NNZ / block, block, 0, stream>>>(
        feat_row, feat_col, feat_vals,
        adj1_row, adj1_col, adj1_vals,
        adj2_row, adj2_col, adj2_vals,
        bcur, gpack1, gmeta1);

    // B: partition bucket -> 64 sub-buckets (XCD-local reads, blockIdx&7 = p).
    subbucket_kernel<<<NPART * BBLK_B, block, 0, stream>>>(
        gpack1, gmeta1, bcur, subcur, gpack2, gmeta2);

    // C1: per-sub-bucket histogram -> cnt (no atomics, covers all slots).
    subhist_kernel<<<NPART * NSUB, 512, 0, stream>>>(gmeta2, subcur, cnt);

    scan_block_kernel<<<SCAN_BLOCKS, 256, 0, stream>>>(cnt, starts, bsum);
    scan_bsum_kernel<<<1, 1024, 0, stream>>>(bsum, SCAN_BLOCKS);
    scan_add_kernel<<<SCAN_BLOCKS, 256, 0, stream>>>(starts, bsum);

    // C2: LDS counting sort per sub-bucket, contiguous coalesced spack writes.
    sort_write_kernel<<<NPART * NSUB, 512, 0, stream>>>(
        gpack2, gmeta2, subcur, starts, spack);

    const int grid_rows = N_NODES / 8;                           // 6250 blocks, 8 rows each
    feat_gather_kernel<<<grid_rows, 256, 0, stream>>>(
        starts, spack, (const float4*)W1, (const float4*)W2, xw1h, xw2h);
    adj_gather_kernel<<<grid_rows, 256, 0, stream>>>(
        starts, spack, xw1h, xw2h, (vf4*)d_out);
}